// Round 2
// baseline (863.033 us; speedup 1.0000x reference)
//
#include <hip/hip_runtime.h>
#include <hip/hip_bf16.h>

// DenseDSSnetwork: 4-layer DSS-GIN over 4096 node-deleted subgraphs + graph branch.
// Inputs fp32, OUTPUT fp32 [64,10]. All heavy matmuls in bf16 MFMA (16x16x32),
// fp32 accumulate; BN stats in fp32. Structural mask: del(s)=s%64, graph(s)=s/64.

typedef __bf16 bf16x8 __attribute__((ext_vector_type(8)));
typedef float f32x4 __attribute__((ext_vector_type(4)));
typedef unsigned short us8 __attribute__((ext_vector_type(8)));
typedef unsigned short us4 __attribute__((ext_vector_type(4)));

__device__ __forceinline__ unsigned short f2b(float f) {
  unsigned u = __builtin_bit_cast(unsigned, f);
  u += 0x7FFFu + ((u >> 16) & 1u);            // RNE
  return (unsigned short)(u >> 16);
}
__device__ __forceinline__ float b2f(unsigned short h) {
  return __builtin_bit_cast(float, (unsigned)h << 16);
}
__device__ __forceinline__ f32x4 mm(bf16x8 a, bf16x8 b, f32x4 c) {
  return __builtin_amdgcn_mfma_f32_16x16x32_bf16(a, b, c, 0, 0, 0);
}
// A/B fragment load from row-major LDS [rows][Kelems] bf16, XOR-swizzled rows.
__device__ __forceinline__ bf16x8 frag(const char* base, int row, int Kelems, int k0) {
  int off = (row * Kelems + k0) * 2;
  off ^= (row & 7) << 4;
  return *(const bf16x8*)(base + off);
}
__device__ __forceinline__ float lk(float v) { return v > 0.f ? v : 0.01f * v; }

// Weight prep: W[k][n] fp32 -> Wt[n][k] bf16, 16 matrices (l*4 + {gW1,gW2,sW1,sW2})
__global__ __launch_bounds__(256) void k_prep(const float* __restrict__ g1,
    const float* __restrict__ g2, const float* __restrict__ s1,
    const float* __restrict__ s2, unsigned short* __restrict__ wt) {
  int b = blockIdx.x;              // 0..15
  int l = b >> 2, j = b & 3;
  const float* src = (j == 0 ? g1 : j == 1 ? g2 : j == 2 ? s1 : s2) + l * 16384;
  unsigned short* dst = wt + b * 16384;
  for (int e = threadIdx.x; e < 16384; e += 256) {
    int n = e >> 7, k = e & 127;
    dst[e] = f2b(src[k * 128 + n]);
  }
}

// x_sum[g,n,d] = mean over 64 subgraphs of x[s,n,d]
__global__ __launch_bounds__(128) void k_segmean(const float* __restrict__ x,
                                                 float* __restrict__ xsum) {
  int gb = blockIdx.x;             // g*64+n
  int g = gb >> 6;
  const float* base = x + ((size_t)g * 64) * 8192 + (size_t)(gb & 63) * 128 + threadIdx.x;
  float s = 0.f;
  #pragma unroll 8
  for (int j = 0; j < 64; ++j) s += base[(size_t)j * 8192];
  xsum[(size_t)gb * 128 + threadIdx.x] = s * (1.0f / 64.0f);
}

// Fused GIN: h = mask*( leaky((ep1*x + adj@x)@W1 + b1) @ W2 + b2 ), + BN col partials.
// One block per (sub)graph, 256 threads = 4 waves, wave w owns output rows w*16..+15.
__global__ __launch_bounds__(256) void k_gin(const float* __restrict__ xsrc,
    const float* __restrict__ adjb, const unsigned short* __restrict__ W1t,
    const unsigned short* __restrict__ W2t, const float* __restrict__ b1,
    const float* __restrict__ b2, const float* __restrict__ epsp,
    unsigned short* __restrict__ hout, float* __restrict__ psum,
    float* __restrict__ psq, int masked) {
  __shared__ __align__(16) char lds[73728];
  char* ldsAdj = lds;              // 8192 : bf16 [64][64]  swz (rowB=128)
  char* ldsXT  = lds + 8192;       // 16384: bf16 [128][64] swz (rowB=128) = x^T
  char* ldsW   = lds + 24576;      // 32768: bf16 [128][128] swz (rowB=256)
  char* ldsT   = lds + 57344;      // 16384: bf16 [64][128] swz (rowB=256)
  float* ldsH  = (float*)ldsW;     // reuse after mm3: f32 [64][128]
  float* ldsR  = (float*)ldsT;     // reuse: 512-float reduce scratch

  const int tid = threadIdx.x;
  const int bid = blockIdx.x;
  const float ep1 = 1.0f + epsp[0];
  const int del = masked ? (bid & 63) : -1;
  const float* xg = xsrc + (size_t)bid * 8192;
  const float* ag = adjb + (size_t)bid * 4096;

  // stage adj fp32->bf16 swz
  for (int e = tid * 4; e < 4096; e += 1024) {
    float4 v = *(const float4*)(ag + e);
    int row = e >> 6;
    int off = (e << 1) ^ ((row & 7) << 4);
    us4 h; h.x = f2b(v.x); h.y = f2b(v.y); h.z = f2b(v.z); h.w = f2b(v.w);
    *(us4*)(ldsAdj + off) = h;
  }
  // stage x transposed fp32->bf16 swz : xT[d][m]
  for (int e = tid * 4; e < 8192; e += 1024) {
    float4 v = *(const float4*)(xg + e);
    int m = e >> 7, d0 = e & 127;
    float vv[4] = {v.x, v.y, v.z, v.w};
    #pragma unroll
    for (int j = 0; j < 4; ++j) {
      int row = d0 + j;
      int off = ((row << 7) + (m << 1)) ^ ((row & 7) << 4);
      *(unsigned short*)(ldsXT + off) = f2b(vv[j]);
    }
  }
  // stage W1t (bf16 global row-major [n][k]) -> ldsW swz
  for (int o = tid * 16; o < 32768; o += 4096) {
    float4 v = *(const float4*)((const char*)W1t + o);
    int row = o >> 8;
    *(float4*)(ldsW + (o ^ ((row & 7) << 4))) = v;
  }
  __syncthreads();

  const int wv = tid >> 6, ln = tid & 63;
  const int lr = ln & 15, lkh = ln >> 4;
  const int arow = wv * 16 + lr;

  // mm1: agg = adj @ x ; t = ep1*x + agg -> ldsT (bf16)
  #pragma unroll
  for (int nt = 0; nt < 8; ++nt) {
    f32x4 acc = {0.f, 0.f, 0.f, 0.f};
    #pragma unroll
    for (int k0 = 0; k0 < 64; k0 += 32) {
      bf16x8 a = frag(ldsAdj, arow, 64, k0 + lkh * 8);
      bf16x8 b = frag(ldsXT, nt * 16 + lr, 64, k0 + lkh * 8);
      acc = mm(a, b, acc);
    }
    int col = nt * 16 + lr;
    #pragma unroll
    for (int r = 0; r < 4; ++r) {
      int row = wv * 16 + lkh * 4 + r;
      int xoff = ((col << 7) + (row << 1)) ^ ((col & 7) << 4);
      float xv = b2f(*(const unsigned short*)(ldsXT + xoff));
      float tv = fmaf(ep1, xv, acc[r]);
      int toff = ((row << 8) + (col << 1)) ^ ((row & 7) << 4);
      *(unsigned short*)(ldsT + toff) = f2b(tv);
    }
  }
  __syncthreads();

  // mm2: u = leaky(t @ W1 + b1) (kept in regs)
  float uf[8][4];
  #pragma unroll
  for (int nt = 0; nt < 8; ++nt) {
    f32x4 acc = {0.f, 0.f, 0.f, 0.f};
    #pragma unroll
    for (int k0 = 0; k0 < 128; k0 += 32) {
      bf16x8 a = frag(ldsT, arow, 128, k0 + lkh * 8);
      bf16x8 b = frag(ldsW, nt * 16 + lr, 128, k0 + lkh * 8);
      acc = mm(a, b, acc);
    }
    float bb = b1[nt * 16 + lr];
    #pragma unroll
    for (int r = 0; r < 4; ++r) uf[nt][r] = lk(acc[r] + bb);
  }
  __syncthreads();
  // write u -> ldsT ; stage W2t -> ldsW
  #pragma unroll
  for (int nt = 0; nt < 8; ++nt) {
    int col = nt * 16 + lr;
    #pragma unroll
    for (int r = 0; r < 4; ++r) {
      int row = wv * 16 + lkh * 4 + r;
      int toff = ((row << 8) + (col << 1)) ^ ((row & 7) << 4);
      *(unsigned short*)(ldsT + toff) = f2b(uf[nt][r]);
    }
  }
  for (int o = tid * 16; o < 32768; o += 4096) {
    float4 v = *(const float4*)((const char*)W2t + o);
    int row = o >> 8;
    *(float4*)(ldsW + (o ^ ((row & 7) << 4))) = v;
  }
  __syncthreads();

  // mm3: h = u @ W2 + b2, mask deleted row
  float hf[8][4];
  #pragma unroll
  for (int nt = 0; nt < 8; ++nt) {
    f32x4 acc = {0.f, 0.f, 0.f, 0.f};
    #pragma unroll
    for (int k0 = 0; k0 < 128; k0 += 32) {
      bf16x8 a = frag(ldsT, arow, 128, k0 + lkh * 8);
      bf16x8 b = frag(ldsW, nt * 16 + lr, 128, k0 + lkh * 8);
      acc = mm(a, b, acc);
    }
    float bb = b2[nt * 16 + lr];
    #pragma unroll
    for (int r = 0; r < 4; ++r) {
      int row = wv * 16 + lkh * 4 + r;
      float v = acc[r] + bb;
      if (row == del) v = 0.f;
      hf[nt][r] = v;
    }
  }
  __syncthreads();                 // all waves done reading ldsW (W2)
  #pragma unroll
  for (int nt = 0; nt < 8; ++nt) {
    int col = nt * 16 + lr;
    #pragma unroll
    for (int r = 0; r < 4; ++r) {
      int row = wv * 16 + lkh * 4 + r;
      ldsH[row * 128 + col] = hf[nt][r];
    }
  }
  __syncthreads();

  // coalesced bf16 global write of h
  size_t gbase = (size_t)bid * 8192;
  for (int e = tid * 8; e < 8192; e += 2048) {
    us8 o;
    #pragma unroll
    for (int j = 0; j < 8; ++j) o[j] = f2b(ldsH[e + j]);
    *(us8*)(hout + gbase + e) = o;
  }
  // BN per-feature partial sums for this block (deleted row contributes 0)
  {
    int d = tid & 127, half = tid >> 7;
    float sm = 0.f, sq = 0.f;
    for (int m = half * 32; m < half * 32 + 32; ++m) {
      float v = ldsH[m * 128 + d];
      sm += v; sq += v * v;
    }
    ldsR[tid] = sm; ldsR[256 + tid] = sq;
    __syncthreads();
    if (tid < 128) {
      psum[(size_t)bid * 128 + tid] = ldsR[tid] + ldsR[tid + 128];
      psq[(size_t)bid * 128 + tid]  = ldsR[256 + tid] + ldsR[256 + tid + 128];
    }
  }
}

// Finalize BN for both branches into fused scale/shift: hn = h*A + B
__global__ __launch_bounds__(256) void k_bnfin(const float* __restrict__ p1s,
    const float* __restrict__ p1q, const float* __restrict__ p2s,
    const float* __restrict__ p2q, const float* __restrict__ gam1,
    const float* __restrict__ bet1, const float* __restrict__ gam2,
    const float* __restrict__ bet2, float* __restrict__ bnA, float* __restrict__ bnB,
    float* __restrict__ bnsA, float* __restrict__ bnsB) {
  __shared__ float red[512];
  __shared__ float red2[128];
  int d = blockIdx.x;              // feature 0..127
  int t = threadIdx.x;
  float s = 0.f, q = 0.f;
  for (int j = t; j < 4096; j += 256) { s += p1s[(size_t)j * 128 + d]; q += p1q[(size_t)j * 128 + d]; }
  red[t] = s; red[256 + t] = q;
  if (t < 64) { red2[t] = p2s[(size_t)t * 128 + d]; red2[64 + t] = p2q[(size_t)t * 128 + d]; }
  __syncthreads();
  for (int w = 128; w > 0; w >>= 1) {
    if (t < w) { red[t] += red[t + w]; red[256 + t] += red[256 + t + w]; }
    __syncthreads();
  }
  for (int w = 32; w > 0; w >>= 1) {
    if (t < w) { red2[t] += red2[t + w]; red2[64 + t] += red2[64 + t + w]; }
    __syncthreads();
  }
  if (t == 0) {
    const float cnt1 = 4096.0f * 63.0f;
    float mean = red[0] / cnt1;
    float var = red[256] / cnt1 - mean * mean;
    float A = gam1[d] * rsqrtf(var + 1e-5f);
    bnA[d] = A; bnB[d] = bet1[d] - mean * A;
    const float cnt2 = 4096.0f;
    float mean2 = red2[0] / cnt2;
    float var2 = red2[64] / cnt2 - mean2 * mean2;
    float A2 = gam2[d] * rsqrtf(var2 + 1e-5f);
    bnsA[d] = A2; bnsB[d] = bet2[d] - mean2 * A2;
  }
}

// x_new = leaky( where(valid, BN1(h1), 0) + BN2(h2[g]) )
__global__ __launch_bounds__(256) void k_combine(const unsigned short* __restrict__ h1,
    const unsigned short* __restrict__ h2, const float* __restrict__ bnA,
    const float* __restrict__ bnB, const float* __restrict__ bnsA,
    const float* __restrict__ bnsB, float* __restrict__ xo) {
  __shared__ float A1[128], B1[128], A2[128], B2[128];
  int tid = threadIdx.x;
  if (tid < 128) { A1[tid] = bnA[tid]; B1[tid] = bnB[tid]; A2[tid] = bnsA[tid]; B2[tid] = bnsB[tid]; }
  __syncthreads();
  int s = blockIdx.x, g = s >> 6, del = s & 63;
  size_t sb = (size_t)s * 8192, gb = (size_t)g * 8192;
  for (int e = tid * 8; e < 8192; e += 2048) {
    int m = e >> 7, d0 = e & 127;
    us8 a = *(const us8*)(h1 + sb + e);
    us8 b = *(const us8*)(h2 + gb + e);
    float vs[8];
    #pragma unroll
    for (int j = 0; j < 8; ++j) {
      int d = d0 + j;
      float hv = (m == del) ? 0.f : fmaf(b2f(a[j]), A1[d], B1[d]);
      float h2v = fmaf(b2f(b[j]), A2[d], B2[d]);
      vs[j] = lk(hv + h2v);
    }
    *(float4*)(xo + sb + e)     = make_float4(vs[0], vs[1], vs[2], vs[3]);
    *(float4*)(xo + sb + e + 4) = make_float4(vs[4], vs[5], vs[6], vs[7]);
  }
}

// partial pool: sum of x over 8 subgraphs x 64 nodes per block
__global__ __launch_bounds__(128) void k_pool(const float* __restrict__ x,
                                              float* __restrict__ pp) {
  int g = blockIdx.x >> 3, p = blockIdx.x & 7;
  const float* base = x + ((size_t)(g * 64 + p * 8)) * 8192 + threadIdx.x;
  float s = 0.f;
  for (int r = 0; r < 512; ++r) s += base[(size_t)r * 128];
  pp[(size_t)blockIdx.x * 128 + threadIdx.x] = s;
}

// final readout MLP per graph, fp32, out fp32
__global__ __launch_bounds__(256) void k_final(const float* __restrict__ pp,
    const float* __restrict__ W1, const float* __restrict__ b1,
    const float* __restrict__ W2, const float* __restrict__ b2,
    float* __restrict__ out) {
  __shared__ float hg[128];
  __shared__ float z[256];
  int g = blockIdx.x, t = threadIdx.x;
  if (t < 128) {
    float s = 0.f;
    #pragma unroll
    for (int p = 0; p < 8; ++p) s += pp[(size_t)(g * 8 + p) * 128 + t];
    hg[t] = s * (1.0f / (64.0f * 63.0f));
  }
  __syncthreads();
  float a = b1[t];
  for (int d = 0; d < 128; ++d) a = fmaf(hg[d], W1[d * 256 + t], a);
  z[t] = lk(a);
  __syncthreads();
  if (t < 10) {
    float o = b2[t];
    for (int j = 0; j < 256; ++j) o = fmaf(z[j], W2[j * 10 + t], o);
    out[g * 10 + t] = o;
  }
}

extern "C" void kernel_launch(void* const* d_in, const int* in_sizes, int n_in,
                              void* d_out, int out_size, void* d_ws, size_t ws_size,
                              hipStream_t stream) {
  (void)in_sizes; (void)n_in; (void)out_size; (void)ws_size;
  const float* x    = (const float*)d_in[0];
  const float* adj  = (const float*)d_in[1];
  const float* oadj = (const float*)d_in[2];
  const float* gW1  = (const float*)d_in[3];
  const float* gb1  = (const float*)d_in[4];
  const float* gW2  = (const float*)d_in[5];
  const float* gb2  = (const float*)d_in[6];
  const float* geps = (const float*)d_in[7];
  const float* sW1  = (const float*)d_in[8];
  const float* sb1  = (const float*)d_in[9];
  const float* sW2  = (const float*)d_in[10];
  const float* sb2  = (const float*)d_in[11];
  const float* seps = (const float*)d_in[12];
  const float* bng  = (const float*)d_in[13];
  const float* bnb  = (const float*)d_in[14];
  const float* bnsg = (const float*)d_in[15];
  const float* bnsb = (const float*)d_in[16];
  const float* fW1  = (const float*)d_in[17];
  const float* fb1  = (const float*)d_in[18];
  const float* fW2  = (const float*)d_in[19];
  const float* fb2  = (const float*)d_in[20];
  float* out = (float*)d_out;

  char* w = (char*)d_ws;
  float* xw = (float*)w;            w += (size_t)134217728;  // x fp32 [4096][64][128]
  unsigned short* h1 = (unsigned short*)w; w += 67108864;    // h1 bf16
  unsigned short* h2 = (unsigned short*)w; w += 1048576;     // h2 bf16 [64][64][128]
  float* xsum = (float*)w;          w += 2097152;            // fp32 [64][64][128]
  unsigned short* wt = (unsigned short*)w; w += 524288;      // 16x bf16 [128][128] W^T
  float* p1s = (float*)w;           w += 2097152;
  float* p1q = (float*)w;           w += 2097152;
  float* p2s = (float*)w;           w += 32768;
  float* p2q = (float*)w;           w += 32768;
  float* bnA = (float*)w;           w += 512;
  float* bnB = (float*)w;           w += 512;
  float* bnsA = (float*)w;          w += 512;
  float* bnsB = (float*)w;          w += 512;
  float* pool = (float*)w;          w += 262144;

  k_prep<<<16, 256, 0, stream>>>(gW1, gW2, sW1, sW2, wt);
  for (int i = 0; i < 4; ++i) {
    const float* xi = (i == 0) ? x : xw;
    k_segmean<<<4096, 128, 0, stream>>>(xi, xsum);
    k_gin<<<4096, 256, 0, stream>>>(xi, adj, wt + (i * 4 + 0) * 16384,
        wt + (i * 4 + 1) * 16384, gb1 + i * 128, gb2 + i * 128, geps + i,
        h1, p1s, p1q, 1);
    k_gin<<<64, 256, 0, stream>>>(xsum, oadj, wt + (i * 4 + 2) * 16384,
        wt + (i * 4 + 3) * 16384, sb1 + i * 128, sb2 + i * 128, seps + i,
        h2, p2s, p2q, 0);
    k_bnfin<<<128, 256, 0, stream>>>(p1s, p1q, p2s, p2q, bng + i * 128,
        bnb + i * 128, bnsg + i * 128, bnsb + i * 128, bnA, bnB, bnsA, bnsB);
    k_combine<<<4096, 256, 0, stream>>>(h1, h2, bnA, bnB, bnsA, bnsB, xw);
  }
  k_pool<<<512, 128, 0, stream>>>(xw, pool);
  k_final<<<64, 256, 0, stream>>>(pool, fW1, fb1, fW2, fb2, out);
}